// Round 4
// baseline (1172.121 us; speedup 1.0000x reference)
//
#include <hip/hip_runtime.h>

typedef __bf16 bf16_t;
typedef __bf16 bf16x8 __attribute__((ext_vector_type(8)));
typedef float f32x4 __attribute__((ext_vector_type(4)));

#define TSEQ 30
#define ISZ  100
#define HSZ  256
#define NB   5120        // LSTM batch
#define BATCH 512
#define G4   1024        // 4*H
#define XP   128         // padded x feature size
#define KP   384         // padded K = XP + HSZ
#define ROWB 768         // KP * 2 bytes per LDS act row
#define NCH  40          // real batch cols per block
#define NPD  48          // padded cols (3 n-frags)
#define WDSZ (2 * G4 * KP)   // per-copy W elements
#define WCOPIES 8

__device__ __forceinline__ float fsig(float x)  { return 1.0f / (1.0f + __expf(-x)); }
__device__ __forceinline__ float ftanh(float x) { return 2.0f / (1.0f + __expf(-2.0f * x)) - 1.0f; }

// ---- prep: weights -> MFMA-fragment layout, replicated x8 (one per XCD) --
// Wf[copy][d][mf 0..63][ks 0..11][lane 0..63][e 0..7]; gate row r = h*4+gate
__global__ void prep_weights(const float* __restrict__ Wih_f, const float* __restrict__ Whh_f,
                             const float* __restrict__ bih_f, const float* __restrict__ bhh_f,
                             const float* __restrict__ Wih_b, const float* __restrict__ Whh_b,
                             const float* __restrict__ bih_b, const float* __restrict__ bhh_b,
                             bf16_t* __restrict__ Wf, float* __restrict__ bias)
{
    int idx = blockIdx.x * 256 + threadIdx.x;          // over 2*1024*384
    if (idx >= 2 * G4 * KP) return;
    int d = idx / (G4 * KP);
    int r = (idx / KP) % G4;
    int k = idx % KP;
    int h = r >> 2, gate = r & 3;
    int grow = gate * HSZ + h;
    const float* Wih = d ? Wih_b : Wih_f;
    const float* Whh = d ? Whh_b : Whh_f;
    float v;
    if (k < ISZ)       v = Wih[grow * ISZ + k];
    else if (k < XP)   v = 0.0f;
    else               v = Whh[grow * HSZ + (k - XP)];
    int mf = r >> 4, lr = r & 15;
    int ks = k >> 5, lq = (k >> 3) & 3, e = k & 7;
    size_t o = ((((size_t)d * 64 + mf) * 12 + ks) * 64 + lq * 16 + lr) * 8 + e;
    bf16_t bv = (bf16_t)v;
#pragma unroll
    for (int c = 0; c < WCOPIES; ++c) Wf[(size_t)c * WDSZ + o] = bv;
    if (k == 0) {
        const float* bih = d ? bih_b : bih_f;
        const float* bhh = d ? bhh_b : bhh_f;
        bias[d * G4 + r] = bih[grow] + bhh[grow];
    }
}

// ---- prep: x -> time-major padded bf16  xTp[t][n][kp<128] ---------------
__global__ void prep_x(const float* __restrict__ x, bf16_t* __restrict__ xTp)
{
    int idx = blockIdx.x * 256 + threadIdx.x;          // over 30*5120*128
    if (idx >= TSEQ * NB * XP) return;
    int t  = idx / (NB * XP);
    int n  = (idx / XP) % NB;
    int kp = idx % XP;
    float v = (kp < ISZ) ? x[(size_t)n * (TSEQ * ISZ) + t * ISZ + kp] : 0.0f;
    xTp[idx] = (bf16_t)v;
}

// ---- prep: transpose W1 for coalesced head ------------------------------
__global__ void prep_w1t(const float* __restrict__ W1, float* __restrict__ W1T)
{
    int idx = blockIdx.x * 256 + threadIdx.x;          // over 2560*64
    if (idx >= 2560 * 64) return;
    int k = idx / 64, j = idx % 64;
    W1T[k * 64 + j] = W1[j * 2560 + k];
}

// ---- persistent LSTM: each block owns (dir, 40 batch cols), all 30 steps -
// grid (128, 2), block 512 (8 waves). Wave w owns gate rows [w*128, w*128+128).
// __launch_bounds__(512,1): 1 block/CU -> 256-VGPR budget, NO spills (r3 lesson:
// (512,2) capped VGPR at 128 and spilled ~70 regs/lane -> GBs of scratch traffic).
__global__ __launch_bounds__(512, 1)
void lstm_persist(const bf16_t* __restrict__ Wf, const float* __restrict__ bias,
                  const bf16_t* __restrict__ xTp, const float* __restrict__ h0,
                  const float* __restrict__ c0, float* __restrict__ hfin)
{
    __shared__ __align__(16) unsigned char smem[4096 + 41120];
    float* biasL = (float*)smem;
    unsigned char* actL = smem + 4096;
    float* hstage = (float*)(smem + 4096);             // overlays actT (only after last step)

    const int dir = blockIdx.y;
    const int n0  = blockIdx.x * NCH;
    const int tid = threadIdx.x;
    const int wave = tid >> 6;
    const int lane = tid & 63;
    const int lr   = lane & 15;
    const int lq   = lane >> 4;

    // copy pick: flat block id & 7 ~ XCD id under round-robin dispatch (perf heuristic)
    const int cp = (blockIdx.x + 128 * blockIdx.y) & 7;
    const bf16_t* wp = Wf + (size_t)cp * WDSZ
                          + (((size_t)dir * 64 + wave * 8) * 12) * 512;

    // --- init: bias -> LDS, zero actT ---
    for (int i = tid; i < G4; i += 512) biasL[i] = bias[dir * G4 + i];
    for (int i = tid; i < NPD * 48; i += 512) {
        uint4 z = {0, 0, 0, 0};
        *(uint4*)(actL + i * 16) = z;
    }
    __syncthreads();
    // --- h0 -> LDS (bf16, swizzled), x(t=0) -> LDS ---
    for (int i = tid; i < NCH * HSZ; i += 512) {
        int n = i >> 8, h = i & 255;
        float v = h0[((size_t)dir * NB + n0 + n) * HSZ + h];
        *(bf16_t*)(actL + n * ROWB + ((256 + 2 * h) ^ ((n & 7) << 4))) = (bf16_t)v;
    }
    {
        int tx0 = dir == 0 ? 0 : TSEQ - 1;
        for (int i = tid; i < NCH * 16; i += 512) {
            int n = i >> 4, ck = i & 15;
            uint4 v = *(const uint4*)(xTp + ((size_t)tx0 * NB + n0 + n) * XP + ck * 8);
            *(uint4*)(actL + n * ROWB + ((ck * 16) ^ ((n & 7) << 4))) = v;
        }
    }
    // --- c0 -> registers (one fp32 per (mf,nf) cell) ---
    float cst[8][3];
#pragma unroll
    for (int mf = 0; mf < 8; ++mf) {
        int h = wave * 32 + mf * 4 + lq;
#pragma unroll
        for (int nf = 0; nf < 3; ++nf) {
            int n = nf * 16 + lr;
            int gn = n0 + (n < NCH ? n : NCH - 1);
            cst[mf][nf] = c0[((size_t)dir * NB + gn) * HSZ + h];
        }
    }

#pragma unroll 1
    for (int t = 0; t < TSEQ; ++t) {
        __syncthreads();                               // actT (h and x) ready

        // --- T14: issue x(t+1) global loads EARLY (consumed after barrier 2) ---
        uint4 xr0, xr1;
        if (t < TSEQ - 1) {
            int tx = dir == 0 ? t + 1 : TSEQ - 2 - t;
            int n = tid >> 4, ck = tid & 15;
            xr0 = *(const uint4*)(xTp + ((size_t)tx * NB + n0 + n) * XP + ck * 8);
            if (tid < 128) {
                int i1 = tid + 512;
                int n1 = i1 >> 4, ck1 = i1 & 15;
                xr1 = *(const uint4*)(xTp + ((size_t)tx * NB + n0 + n1) * XP + ck1 * 8);
            }
        }

        // --- MFMA loop: per-ks W fragment loads (L2-hit streams) ---
        f32x4 acc[8][3] = {};
#pragma unroll
        for (int ks = 0; ks < 12; ++ks) {
            bf16x8 b[3];
#pragma unroll
            for (int nf = 0; nf < 3; ++nf) {
                int row = nf * 16 + lr;
                b[nf] = *(const bf16x8*)(actL + row * ROWB + ((ks * 64 + lq * 16) ^ ((row & 7) << 4)));
            }
            bf16x8 aC[8];
#pragma unroll
            for (int mf = 0; mf < 8; ++mf)
                aC[mf] = *(const bf16x8*)(wp + (((size_t)mf * 12 + ks) * 64 + lane) * 8);
#pragma unroll
            for (int mf = 0; mf < 8; ++mf) {
                acc[mf][0] = __builtin_amdgcn_mfma_f32_16x16x32_bf16(aC[mf], b[0], acc[mf][0], 0, 0, 0);
                acc[mf][1] = __builtin_amdgcn_mfma_f32_16x16x32_bf16(aC[mf], b[1], acc[mf][1], 0, 0, 0);
                acc[mf][2] = __builtin_amdgcn_mfma_f32_16x16x32_bf16(aC[mf], b[2], acc[mf][2], 0, 0, 0);
            }
        }
        __syncthreads();                               // all actT reads done

        // --- x(t+1) regs -> LDS (region disjoint from h writes) ---
        if (t < TSEQ - 1) {
            int n = tid >> 4, ck = tid & 15;
            *(uint4*)(actL + n * ROWB + ((ck * 16) ^ ((n & 7) << 4))) = xr0;
            if (tid < 128) {
                int i1 = tid + 512;
                int n1 = i1 >> 4, ck1 = i1 & 15;
                *(uint4*)(actL + n1 * ROWB + ((ck1 * 16) ^ ((n1 & 7) << 4))) = xr1;
            }
        }

        // --- gates + state update; h -> LDS (or hstage on last step) ---
#pragma unroll
        for (int mf = 0; mf < 8; ++mf) {
            int h = wave * 32 + mf * 4 + lq;
            float4 bb = *(const float4*)(biasL + 4 * h);
#pragma unroll
            for (int nf = 0; nf < 3; ++nf) {
                int n = nf * 16 + lr;
                f32x4 g = acc[mf][nf];
                float gi = fsig(g[0] + bb.x);
                float gf = fsig(g[1] + bb.y);
                float gg = ftanh(g[2] + bb.z);
                float go = fsig(g[3] + bb.w);
                float cn = gf * cst[mf][nf] + gi * gg;
                cst[mf][nf] = cn;
                float hn = go * ftanh(cn);
                if (n < NCH) {
                    if (t < TSEQ - 1)
                        *(bf16_t*)(actL + n * ROWB + ((256 + 2 * h) ^ ((n & 7) << 4))) = (bf16_t)hn;
                    else
                        hstage[n * 257 + h] = hn;
                }
            }
        }
    }
    __syncthreads();
    // --- coalesced hfin write from hstage ---
    for (int i = tid; i < NCH * HSZ; i += 512) {
        int n = i >> 8, h = i & 255;
        hfin[((size_t)dir * NB + n0 + n) * HSZ + h] = hstage[n * 257 + h];
    }
}

// ---- head: x_fea assembly + Linear(2560,64) + Linear(64,5) + softmax ----
__global__ __launch_bounds__(256)
void head_kernel(const float* __restrict__ hfin, const float* __restrict__ W1T,
                 const float* __restrict__ b1, const float* __restrict__ W2,
                 const float* __restrict__ b2, float* __restrict__ out)
{
    __shared__ float flat_s[2560];
    __shared__ float partial[4][64];
    __shared__ float zs[64];
    __shared__ float ls[5];
    __shared__ float es[5];
    int b = blockIdx.x, tid = threadIdx.x;
    const float* hF = hfin;
    const float* hB = hfin + (size_t)NB * HSZ;
    float* xfea = out + BATCH * 5 + (size_t)b * 2560;

    for (int j = tid; j < 2560; j += 256) {
        int s = j >> 8, c = j & 255;
        int n = b * 10 + s;
        float v = (c < 128) ? hF[(size_t)n * HSZ + c] : hB[(size_t)n * HSZ + c];
        flat_s[j] = v;
        xfea[j] = v;
    }
    __syncthreads();
    int j = tid & 63, q = tid >> 6;
    float sum = 0.0f;
    for (int k = q * 640; k < (q + 1) * 640; ++k) sum += flat_s[k] * W1T[k * 64 + j];
    partial[q][j] = sum;
    __syncthreads();
    if (tid < 64) zs[tid] = partial[0][tid] + partial[1][tid] + partial[2][tid] + partial[3][tid] + b1[tid];
    __syncthreads();
    if (tid < 5) {
        float l = b2[tid];
        for (int k = 0; k < 64; ++k) l += zs[k] * W2[tid * 64 + k];
        ls[tid] = l;
    }
    __syncthreads();
    if (tid < 5) {
        float m = ls[0];
        for (int k = 1; k < 5; ++k) m = fmaxf(m, ls[k]);
        es[tid] = __expf(ls[tid] - m);
    }
    __syncthreads();
    if (tid < 5) {
        float s5 = es[0] + es[1] + es[2] + es[3] + es[4];
        out[b * 5 + tid] = es[tid] / s5;
    }
}

extern "C" void kernel_launch(void* const* d_in, const int* in_sizes, int n_in,
                              void* d_out, int out_size, void* d_ws, size_t ws_size,
                              hipStream_t stream) {
    const float* x     = (const float*)d_in[0];
    const float* h0    = (const float*)d_in[1];
    const float* c0    = (const float*)d_in[2];
    const float* Wih_f = (const float*)d_in[3];
    const float* Whh_f = (const float*)d_in[4];
    const float* bih_f = (const float*)d_in[5];
    const float* bhh_f = (const float*)d_in[6];
    const float* Wih_b = (const float*)d_in[7];
    const float* Whh_b = (const float*)d_in[8];
    const float* bih_b = (const float*)d_in[9];
    const float* bhh_b = (const float*)d_in[10];
    const float* W1    = (const float*)d_in[11];
    const float* b1    = (const float*)d_in[12];
    const float* W2    = (const float*)d_in[13];
    const float* b2    = (const float*)d_in[14];
    float* out = (float*)d_out;

    uintptr_t ws = (uintptr_t)d_ws;
    bf16_t* Wf   = (bf16_t*)(ws);                      // 8*2*1024*384*2 = 12,582,912
    float*  bias = (float*)(ws + 12582912);            // 2*1024*4       = 8,192
    bf16_t* xTp  = (bf16_t*)(ws + 12591104);           // 30*5120*128*2  = 39,321,600
    float*  hfin = (float*)(ws + 51912704);            // 2*5120*256*4   = 10,485,760
    float*  W1T  = (float*)(ws + 62398464);            // 2560*64*4      = 655,360

    prep_weights<<<(2 * G4 * KP + 255) / 256, 256, 0, stream>>>(
        Wih_f, Whh_f, bih_f, bhh_f, Wih_b, Whh_b, bih_b, bhh_b, Wf, bias);
    prep_x<<<(TSEQ * NB * XP + 255) / 256, 256, 0, stream>>>(x, xTp);
    prep_w1t<<<(2560 * 64 + 255) / 256, 256, 0, stream>>>(W1, W1T);

    lstm_persist<<<dim3(128, 2), 512, 0, stream>>>(Wf, bias, xTp, h0, c0, hfin);
    head_kernel<<<BATCH, 256, 0, stream>>>(hfin, W1T, b1, W2, b2, out);
}

// Round 5
// 1136.107 us; speedup vs baseline: 1.0317x; 1.0317x over previous
//
#include <hip/hip_runtime.h>

typedef __bf16 bf16_t;
typedef __bf16 bf16x8 __attribute__((ext_vector_type(8)));
typedef float f32x4 __attribute__((ext_vector_type(4)));

#define TSEQ 30
#define ISZ  100
#define HSZ  256
#define NB   5120        // LSTM batch
#define BATCH 512
#define G4   1024        // 4*H
#define XP   128         // padded x feature size
#define KP   384         // padded K = XP + HSZ
#define ROWB 768         // KP * 2 bytes per LDS act row
#define NCH  40          // real batch cols per block
#define NPD  48          // padded cols (3 n-frags)

__device__ __forceinline__ float fsig(float x)  { return 1.0f / (1.0f + __expf(-x)); }
__device__ __forceinline__ float ftanh(float x) { return 2.0f / (1.0f + __expf(-2.0f * x)) - 1.0f; }

// ---- prep: weights -> MFMA-fragment layout, fold biases ------------------
// Wf[d][mf 0..63][ks 0..11][lane 0..63][e 0..7]; gate row r = h*4+gate
__global__ void prep_weights(const float* __restrict__ Wih_f, const float* __restrict__ Whh_f,
                             const float* __restrict__ bih_f, const float* __restrict__ bhh_f,
                             const float* __restrict__ Wih_b, const float* __restrict__ Whh_b,
                             const float* __restrict__ bih_b, const float* __restrict__ bhh_b,
                             bf16_t* __restrict__ Wf, float* __restrict__ bias)
{
    int idx = blockIdx.x * 256 + threadIdx.x;          // over 2*1024*384
    if (idx >= 2 * G4 * KP) return;
    int d = idx / (G4 * KP);
    int r = (idx / KP) % G4;
    int k = idx % KP;
    int h = r >> 2, gate = r & 3;
    int grow = gate * HSZ + h;
    const float* Wih = d ? Wih_b : Wih_f;
    const float* Whh = d ? Whh_b : Whh_f;
    float v;
    if (k < ISZ)       v = Wih[grow * ISZ + k];
    else if (k < XP)   v = 0.0f;
    else               v = Whh[grow * HSZ + (k - XP)];
    int mf = r >> 4, lr = r & 15;
    int ks = k >> 5, lq = (k >> 3) & 3, e = k & 7;
    size_t o = ((((size_t)d * 64 + mf) * 12 + ks) * 64 + lq * 16 + lr) * 8 + e;
    Wf[o] = (bf16_t)v;
    if (k == 0) {
        const float* bih = d ? bih_b : bih_f;
        const float* bhh = d ? bhh_b : bhh_f;
        bias[d * G4 + r] = bih[grow] + bhh[grow];
    }
}

// ---- prep: x -> time-major padded bf16  xTp[t][n][kp<128] ---------------
__global__ void prep_x(const float* __restrict__ x, bf16_t* __restrict__ xTp)
{
    int idx = blockIdx.x * 256 + threadIdx.x;          // over 30*5120*128
    if (idx >= TSEQ * NB * XP) return;
    int t  = idx / (NB * XP);
    int n  = (idx / XP) % NB;
    int kp = idx % XP;
    float v = (kp < ISZ) ? x[(size_t)n * (TSEQ * ISZ) + t * ISZ + kp] : 0.0f;
    xTp[idx] = (bf16_t)v;
}

// ---- prep: transpose W1 for coalesced head ------------------------------
__global__ void prep_w1t(const float* __restrict__ W1, float* __restrict__ W1T)
{
    int idx = blockIdx.x * 256 + threadIdx.x;          // over 2560*64
    if (idx >= 2560 * 64) return;
    int k = idx / 64, j = idx % 64;
    W1T[k * 64 + j] = W1[j * 2560 + k];
}

// ---- persistent LSTM: each block owns (dir, 40 batch cols), all 30 steps -
// grid (128, 2), block 512 (8 waves). Wave w owns gate rows [w*128, w*128+128).
// amdgpu_waves_per_eu(2,2): FORCE the 256 VGPR/lane budget (r4 lesson:
// launch_bounds(512,1) left the allocator at 128 VGPR -> ~17 regs/lane spilled
// per step -> 268MB scratch writes -> scratch evicted W from L2 -> 2.7GB FETCH).
__global__ __attribute__((amdgpu_flat_work_group_size(512, 512), amdgpu_waves_per_eu(2, 2)))
void lstm_persist(const bf16_t* __restrict__ Wf, const float* __restrict__ bias,
                  const bf16_t* __restrict__ xTp, const float* __restrict__ h0,
                  const float* __restrict__ c0, float* __restrict__ hfin)
{
    __shared__ __align__(16) unsigned char smem[4096 + 41120];
    float* biasL = (float*)smem;
    unsigned char* actL = smem + 4096;
    float* hstage = (float*)(smem + 4096);             // overlays actT (only after last step)

    const int dir = blockIdx.y;
    const int n0  = blockIdx.x * NCH;
    const int tid = threadIdx.x;
    const int wave = tid >> 6;
    const int lane = tid & 63;
    const int lr   = lane & 15;
    const int lq   = lane >> 4;

    const bf16_t* wp = Wf + (((size_t)dir * 64 + wave * 8) * 12) * 512;

    // --- init: bias -> LDS, zero actT ---
    for (int i = tid; i < G4; i += 512) biasL[i] = bias[dir * G4 + i];
    for (int i = tid; i < NPD * 48; i += 512) {
        uint4 z = {0, 0, 0, 0};
        *(uint4*)(actL + i * 16) = z;
    }
    __syncthreads();
    // --- h0 -> LDS (bf16, swizzled), x(t=0) -> LDS ---
    for (int i = tid; i < NCH * HSZ; i += 512) {
        int n = i >> 8, h = i & 255;
        float v = h0[((size_t)dir * NB + n0 + n) * HSZ + h];
        *(bf16_t*)(actL + n * ROWB + ((256 + 2 * h) ^ ((n & 7) << 4))) = (bf16_t)v;
    }
    {
        int tx0 = dir == 0 ? 0 : TSEQ - 1;
        for (int i = tid; i < NCH * 16; i += 512) {
            int n = i >> 4, ck = i & 15;
            uint4 v = *(const uint4*)(xTp + ((size_t)tx0 * NB + n0 + n) * XP + ck * 8);
            *(uint4*)(actL + n * ROWB + ((ck * 16) ^ ((n & 7) << 4))) = v;
        }
    }
    // --- c0 -> registers (one fp32 per (mf,nf) cell) ---
    float cst[8][3];
#pragma unroll
    for (int mf = 0; mf < 8; ++mf) {
        int h = wave * 32 + mf * 4 + lq;
#pragma unroll
        for (int nf = 0; nf < 3; ++nf) {
            int n = nf * 16 + lr;
            int gn = n0 + (n < NCH ? n : NCH - 1);
            cst[mf][nf] = c0[((size_t)dir * NB + gn) * HSZ + h];
        }
    }

#pragma unroll 1
    for (int t = 0; t < TSEQ; ++t) {
        __syncthreads();                               // actT (h and x) ready

        // --- T14: issue x(t+1) global loads EARLY (consumed after barrier 2) ---
        uint4 xr0, xr1;
        if (t < TSEQ - 1) {
            int tx = dir == 0 ? t + 1 : TSEQ - 2 - t;
            int n = tid >> 4, ck = tid & 15;
            xr0 = *(const uint4*)(xTp + ((size_t)tx * NB + n0 + n) * XP + ck * 8);
            if (tid < 128) {
                int i1 = tid + 512;
                int n1 = i1 >> 4, ck1 = i1 & 15;
                xr1 = *(const uint4*)(xTp + ((size_t)tx * NB + n0 + n1) * XP + ck1 * 8);
            }
        }

        // --- MFMA loop: per-ks W fragment loads (L2-hit streams) ---
        f32x4 acc[8][3] = {};
#pragma unroll
        for (int ks = 0; ks < 12; ++ks) {
            bf16x8 b[3];
#pragma unroll
            for (int nf = 0; nf < 3; ++nf) {
                int row = nf * 16 + lr;
                b[nf] = *(const bf16x8*)(actL + row * ROWB + ((ks * 64 + lq * 16) ^ ((row & 7) << 4)));
            }
            bf16x8 aC[8];
#pragma unroll
            for (int mf = 0; mf < 8; ++mf)
                aC[mf] = *(const bf16x8*)(wp + (((size_t)mf * 12 + ks) * 64 + lane) * 8);
#pragma unroll
            for (int mf = 0; mf < 8; ++mf) {
                acc[mf][0] = __builtin_amdgcn_mfma_f32_16x16x32_bf16(aC[mf], b[0], acc[mf][0], 0, 0, 0);
                acc[mf][1] = __builtin_amdgcn_mfma_f32_16x16x32_bf16(aC[mf], b[1], acc[mf][1], 0, 0, 0);
                acc[mf][2] = __builtin_amdgcn_mfma_f32_16x16x32_bf16(aC[mf], b[2], acc[mf][2], 0, 0, 0);
            }
        }
        __syncthreads();                               // all actT reads done

        // --- x(t+1) regs -> LDS (region disjoint from h writes) ---
        if (t < TSEQ - 1) {
            int n = tid >> 4, ck = tid & 15;
            *(uint4*)(actL + n * ROWB + ((ck * 16) ^ ((n & 7) << 4))) = xr0;
            if (tid < 128) {
                int i1 = tid + 512;
                int n1 = i1 >> 4, ck1 = i1 & 15;
                *(uint4*)(actL + n1 * ROWB + ((ck1 * 16) ^ ((n1 & 7) << 4))) = xr1;
            }
        }

        // --- gates + state update; h -> LDS (or hstage on last step) ---
#pragma unroll
        for (int mf = 0; mf < 8; ++mf) {
            int h = wave * 32 + mf * 4 + lq;
            float4 bb = *(const float4*)(biasL + 4 * h);
#pragma unroll
            for (int nf = 0; nf < 3; ++nf) {
                int n = nf * 16 + lr;
                f32x4 g = acc[mf][nf];
                float gi = fsig(g[0] + bb.x);
                float gf = fsig(g[1] + bb.y);
                float gg = ftanh(g[2] + bb.z);
                float go = fsig(g[3] + bb.w);
                float cn = gf * cst[mf][nf] + gi * gg;
                cst[mf][nf] = cn;
                float hn = go * ftanh(cn);
                if (n < NCH) {
                    if (t < TSEQ - 1)
                        *(bf16_t*)(actL + n * ROWB + ((256 + 2 * h) ^ ((n & 7) << 4))) = (bf16_t)hn;
                    else
                        hstage[n * 257 + h] = hn;
                }
            }
        }
    }
    __syncthreads();
    // --- coalesced hfin write from hstage ---
    for (int i = tid; i < NCH * HSZ; i += 512) {
        int n = i >> 8, h = i & 255;
        hfin[((size_t)dir * NB + n0 + n) * HSZ + h] = hstage[n * 257 + h];
    }
}

// ---- head: x_fea assembly + Linear(2560,64) + Linear(64,5) + softmax ----
__global__ __launch_bounds__(256)
void head_kernel(const float* __restrict__ hfin, const float* __restrict__ W1T,
                 const float* __restrict__ b1, const float* __restrict__ W2,
                 const float* __restrict__ b2, float* __restrict__ out)
{
    __shared__ float flat_s[2560];
    __shared__ float partial[4][64];
    __shared__ float zs[64];
    __shared__ float ls[5];
    __shared__ float es[5];
    int b = blockIdx.x, tid = threadIdx.x;
    const float* hF = hfin;
    const float* hB = hfin + (size_t)NB * HSZ;
    float* xfea = out + BATCH * 5 + (size_t)b * 2560;

    for (int j = tid; j < 2560; j += 256) {
        int s = j >> 8, c = j & 255;
        int n = b * 10 + s;
        float v = (c < 128) ? hF[(size_t)n * HSZ + c] : hB[(size_t)n * HSZ + c];
        flat_s[j] = v;
        xfea[j] = v;
    }
    __syncthreads();
    int j = tid & 63, q = tid >> 6;
    float sum = 0.0f;
    for (int k = q * 640; k < (q + 1) * 640; ++k) sum += flat_s[k] * W1T[k * 64 + j];
    partial[q][j] = sum;
    __syncthreads();
    if (tid < 64) zs[tid] = partial[0][tid] + partial[1][tid] + partial[2][tid] + partial[3][tid] + b1[tid];
    __syncthreads();
    if (tid < 5) {
        float l = b2[tid];
        for (int k = 0; k < 64; ++k) l += zs[k] * W2[tid * 64 + k];
        ls[tid] = l;
    }
    __syncthreads();
    if (tid < 5) {
        float m = ls[0];
        for (int k = 1; k < 5; ++k) m = fmaxf(m, ls[k]);
        es[tid] = __expf(ls[tid] - m);
    }
    __syncthreads();
    if (tid < 5) {
        float s5 = es[0] + es[1] + es[2] + es[3] + es[4];
        out[b * 5 + tid] = es[tid] / s5;
    }
}

extern "C" void kernel_launch(void* const* d_in, const int* in_sizes, int n_in,
                              void* d_out, int out_size, void* d_ws, size_t ws_size,
                              hipStream_t stream) {
    const float* x     = (const float*)d_in[0];
    const float* h0    = (const float*)d_in[1];
    const float* c0    = (const float*)d_in[2];
    const float* Wih_f = (const float*)d_in[3];
    const float* Whh_f = (const float*)d_in[4];
    const float* bih_f = (const float*)d_in[5];
    const float* bhh_f = (const float*)d_in[6];
    const float* Wih_b = (const float*)d_in[7];
    const float* Whh_b = (const float*)d_in[8];
    const float* bih_b = (const float*)d_in[9];
    const float* bhh_b = (const float*)d_in[10];
    const float* W1    = (const float*)d_in[11];
    const float* b1    = (const float*)d_in[12];
    const float* W2    = (const float*)d_in[13];
    const float* b2    = (const float*)d_in[14];
    float* out = (float*)d_out;

    uintptr_t ws = (uintptr_t)d_ws;
    bf16_t* Wf   = (bf16_t*)(ws);                      // 2*1024*384*2   = 1,572,864
    float*  bias = (float*)(ws + 1572864);             // 2*1024*4       = 8,192
    bf16_t* xTp  = (bf16_t*)(ws + 1581056);            // 30*5120*128*2  = 39,321,600
    float*  hfin = (float*)(ws + 40902656);            // 2*5120*256*4   = 10,485,760
    float*  W1T  = (float*)(ws + 51388416);            // 2560*64*4      = 655,360

    prep_weights<<<(2 * G4 * KP + 255) / 256, 256, 0, stream>>>(
        Wih_f, Whh_f, bih_f, bhh_f, Wih_b, Whh_b, bih_b, bhh_b, Wf, bias);
    prep_x<<<(TSEQ * NB * XP + 255) / 256, 256, 0, stream>>>(x, xTp);
    prep_w1t<<<(2560 * 64 + 255) / 256, 256, 0, stream>>>(W1, W1T);

    lstm_persist<<<dim3(128, 2), 512, 0, stream>>>(Wf, bias, xTp, h0, c0, hfin);
    head_kernel<<<BATCH, 256, 0, stream>>>(hfin, W1T, b1, W2, b2, out);
}